// Round 13
// baseline (516.782 us; speedup 1.0000x reference)
//
#include <hip/hip_runtime.h>

#define B_ 16
#define N_ 8192
#define D_ 512
#define M_ 1024
#define BT 32
#define SCALE 0.04419417382415922f  // 1/sqrt(512)

typedef __attribute__((ext_vector_type(8))) short short8;
typedef __attribute__((ext_vector_type(4))) float f32x4;
typedef __attribute__((ext_vector_type(16))) float f32x16;

__device__ __forceinline__ unsigned short f2bf(float f) {
  unsigned int u = __float_as_uint(f);
  u += 0x7FFFu + ((u >> 16) & 1u);  // RNE
  return (unsigned short)(u >> 16);
}
__device__ __forceinline__ float bf2f(unsigned short h) {
  return __uint_as_float(((unsigned int)h) << 16);
}

#define MFMA32(a, b, c) __builtin_amdgcn_mfma_f32_32x32x16_bf16((a), (b), (c), 0, 0, 0)

// memTbF: GEMM1 A-frags (scaled mem, rows=m), block (MT 0..31, kk 0..31):
//   elem[l][j] = SCALE*mem[kk*16 + (l>>5)*8 + j][MT*32 + (l&31)]
// memDF: GEMM2 B-frags (mem, cols=d), block (DT 0..15, kg 0..63), with the
//   softmax-permutation pi on k matching kernel A's natural P write order:
//   storage k = kg*16 + hi*8 + j  ->  logical m = (kg>>1)*32 + 16*(kg&1)
//                                        + 4*hi + (j&3) + 8*(j>>2)
__global__ void prep_mem_kernel(const float* __restrict__ mem,
                                unsigned short* __restrict__ memTbF,
                                unsigned short* __restrict__ memDF) {
  int t = blockIdx.x * 256 + threadIdx.x;  // 0 .. D*M-1
  int j = t & 7, l = (t >> 3) & 63, blk = t >> 9;
  {
    int kk = blk & 31, MT = blk >> 5;
    int m = MT * 32 + (l & 31);
    int d = kk * 16 + ((l >> 5) << 3) + j;
    memTbF[t] = f2bf(mem[d * M_ + m] * SCALE);
  }
  {
    int kg = blk & 63, DT = blk >> 6;
    int d = DT * 32 + (l & 31);
    int hi = l >> 5;
    int m = (kg >> 1) * 32 + ((kg & 1) << 4) + (hi << 2) + (j & 3) + ((j >> 2) << 3);
    memDF[t] = f2bf(mem[d * M_ + m]);
  }
}

// Kernel A: P = exp(x*mem/sqrt(D)) -> bf16 frag-blocks in Pf (= d_out), plus
// per-token denominator reciprocals. Barrier-free main loop; 32-token tile.
__global__ __launch_bounds__(256, 3) void gemm1_exp_kernel(
    const float* __restrict__ x, const unsigned short* __restrict__ memTbF,
    unsigned short* __restrict__ Pf, float* __restrict__ denomInv) {
  __shared__ unsigned short sX[16384];  // 32 KB: X bf16, 32 rows x 1024B, swizzled
  __shared__ float psums[4][32];

  const int tid = threadIdx.x;
  const int w = tid >> 6;     // wave 0..3
  const int lane = tid & 63;
  const int c31 = lane & 31;
  const int l5 = lane >> 5;
  const int e7 = lane & 7;
  const long t0 = (long)blockIdx.x * BT;

  // ---- Stage X -> bf16 -> swizzled sX (slot' = slot ^ (row&7), 16B slots) ----
  {
    const int row = tid >> 3;       // 0..31
    const int cslot = tid & 7;
    const int r7 = row & 7;
    const float* xp = x + (t0 + row) * (long)D_;
    char* sxb = (char*)sX + (row << 10);
#pragma unroll
    for (int j = 0; j < 8; j++) {
      const int s = cslot + 8 * j;  // 16B-slot 0..63 within the row
      f32x4 v0 = *(const f32x4*)(xp + s * 8);
      f32x4 v1 = *(const f32x4*)(xp + s * 8 + 4);
      short8 o;
      o[0] = (short)f2bf(v0[0]);
      o[1] = (short)f2bf(v0[1]);
      o[2] = (short)f2bf(v0[2]);
      o[3] = (short)f2bf(v0[3]);
      o[4] = (short)f2bf(v1[0]);
      o[5] = (short)f2bf(v1[1]);
      o[6] = (short)f2bf(v1[2]);
      o[7] = (short)f2bf(v1[3]);
      *(short8*)(sxb + ((s ^ r7) << 4)) = o;
    }
  }
  __syncthreads();

  char* const bx0 = (char*)sX + (c31 << 10);
  short8* const Pf8 = (short8*)Pf;
  float fsum = 0.f;

  // exp + pack + store one 32x32 S-tile
  auto emit = [&](f32x16 sv, int mtile) {
    unsigned short pb[16];
    float s = 0.f;
#pragma unroll
    for (int q = 0; q < 16; q++) {
      float p = __expf(sv[q]);
      unsigned short b = f2bf(p);
      pb[q] = b;
      s += bf2f(b);  // sum the rounded values GEMM2 will use
    }
    fsum += s;
#pragma unroll
    for (int sb = 0; sb < 2; sb++) {
      short8 o;
#pragma unroll
      for (int e = 0; e < 8; e++) o[e] = (short)pb[sb * 8 + e];
      Pf8[((size_t)blockIdx.x * 64 + (size_t)(mtile * 2 + sb)) * 64 + lane] = o;
    }
  };

#pragma unroll 1
  for (int i = 0; i < 2; i++) {
    const int mt0 = i * 16 + w * 4;  // this wave's 4 m-tiles
    f32x16 s0 = (f32x16)0.0f, s1 = (f32x16)0.0f;
    f32x16 s2 = (f32x16)0.0f, s3 = (f32x16)0.0f;
    const short8* ga = (const short8*)memTbF + (size_t)(mt0 * 32) * 64 + lane;
#pragma unroll 8
    for (int kk = 0; kk < 32; kk++) {
      short8 a0 = ga[(0 * 32 + kk) * 64];
      short8 a1 = ga[(1 * 32 + kk) * 64];
      short8 a2 = ga[(2 * 32 + kk) * 64];
      short8 a3 = ga[(3 * 32 + kk) * 64];
      int sw = (((kk << 1) | l5) ^ e7) << 4;
      short8 x0 = *(const short8*)(bx0 + sw);
      s0 = MFMA32(a0, x0, s0);
      s1 = MFMA32(a1, x0, s1);
      s2 = MFMA32(a2, x0, s2);
      s3 = MFMA32(a3, x0, s3);
    }
    emit(s0, mt0);
    emit(s1, mt0 + 1);
    emit(s2, mt0 + 2);
    emit(s3, mt0 + 3);
  }

  // ---- Denominator reduce ----
  fsum += __shfl_xor(fsum, 32);
  if (l5 == 0) psums[w][c31] = fsum;
  __syncthreads();
  if (tid < BT)
    denomInv[t0 + tid] =
        1.0f / (psums[0][tid] + psums[1][tid] + psums[2][tid] + psums[3][tid]);
}

// Kernel B: out = (P * mem) * (1/denom). Pure barrier-free GEMM; one 32-token
// tile per WG; P-frags stream from HBM (each block read once), memDF from L2.
// Each WG's out window is exactly its own P window (RAW legal after the sync).
__global__ __launch_bounds__(256, 3) void gemm2_kernel(
    const unsigned short* __restrict__ Pf, const unsigned short* __restrict__ memDF,
    const float* __restrict__ denomInv, float* __restrict__ out) {
  __shared__ float sInv[BT];
  const int tid = threadIdx.x;
  const int w = tid >> 6;     // wave 0..3 -> d-slice w*128
  const int lane = tid & 63;
  const int c31 = lane & 31;
  const int l5 = lane >> 5;
  const long t0 = (long)blockIdx.x * BT;
  if (tid < BT) sInv[tid] = denomInv[t0 + tid];

  f32x16 oacc[4];
#pragma unroll
  for (int d0 = 0; d0 < 4; d0++) oacc[d0] = (f32x16)0.0f;

  const short8* pa = (const short8*)Pf + (size_t)blockIdx.x * 4096 + lane;
  const short8* gb = (const short8*)memDF + (size_t)(w * 4) * 4096 + lane;

#pragma unroll 8
  for (int kg = 0; kg < 64; kg++) {
    short8 p = pa[kg * 64];
    short8 b0 = gb[(0 * 64 + kg) * 64];
    short8 b1 = gb[(1 * 64 + kg) * 64];
    short8 b2 = gb[(2 * 64 + kg) * 64];
    short8 b3 = gb[(3 * 64 + kg) * 64];
    oacc[0] = MFMA32(p, b0, oacc[0]);
    oacc[1] = MFMA32(p, b1, oacc[1]);
    oacc[2] = MFMA32(p, b2, oacc[2]);
    oacc[3] = MFMA32(p, b3, oacc[3]);
  }

  __syncthreads();  // all P reads complete (vmcnt drain) + sInv staged

  // ---- Epilogue: overwrite this WG's P window with out = O * (1/sum) ----
#pragma unroll
  for (int q = 0; q < 16; q++) {
    int tok = (q & 3) + ((q >> 2) << 3) + (l5 << 2);
    float inv = sInv[tok];
    float* op = out + (t0 + tok) * (long)D_ + w * 128 + c31;
#pragma unroll
    for (int d0 = 0; d0 < 4; d0++) op[d0 * 32] = oacc[d0][q] * inv;
  }
}

extern "C" void kernel_launch(void* const* d_in, const int* in_sizes, int n_in,
                              void* d_out, int out_size, void* d_ws, size_t ws_size,
                              hipStream_t stream) {
  const float* x = (const float*)d_in[0];
  const float* mem = (const float*)d_in[1];
  float* out = (float*)d_out;
  unsigned short* memTbF = (unsigned short*)d_ws;    // 1 MB frag-layout (scaled)
  unsigned short* memDF = memTbF + (size_t)D_ * M_;  // 1 MB frag-layout (pi-permuted k)
  float* denomInv = (float*)(memDF + (size_t)D_ * M_);  // 512 KB
  unsigned short* Pf = (unsigned short*)d_out;       // P bf16 == d_out byte-size

  hipLaunchKernelGGL(prep_mem_kernel, dim3((D_ * M_) / 256), dim3(256), 0, stream,
                     mem, memTbF, memDF);
  hipLaunchKernelGGL(gemm1_exp_kernel, dim3((B_ * N_) / BT), dim3(256), 0, stream,
                     x, memTbF, Pf, denomInv);
  hipLaunchKernelGGL(gemm2_kernel, dim3((B_ * N_) / BT), dim3(256), 0, stream,
                     Pf, memDF, denomInv, out);
}